// Round 1
// baseline (2834.583 us; speedup 1.0000x reference)
//
#include <hip/hip_runtime.h>

// ============================================================================
// GRU seq2seq (3-layer enc + 3-cell dec + linear), B=2048, H=60, F=1, fp32.
//
// Design (round 0):
//  - Two fused persistent kernels (encoder phase, decoder phase), each a
//    3-stage pipeline: wave-group g computes layer/cell g at t = slot - g,
//    passing activations via a 2-deep LDS ring. No inter-layer HBM traffic.
//  - 128 blocks x 768 threads (12 waves). Block owns 16 batch rows.
//    4 waves per layer; wave w owns gate-column tiles {w, w+4, w+8} of the
//    [16 x 192] gate matrix (r: cols 0-63, z: 64-127, n: 128-191; 60->64 pad)
//    so (r,z,n) of a unit share a lane in the MFMA C layout.
//  - Numerics: bf16 hi/lo split for both A (h/x) and B (weights); 3 MFMA
//    products (hi*Whi + lo*Whi + hi*Wlo) => ~2^-17 relative operand error,
//    fp32 accumulate; h recurrence itself kept in full fp32 registers.
//    din=1 inputs (enc L0 / dec cell1) use exact scalar fp32 VALU path.
//  - Weights live in VGPRs (24 B-frags/wave = 96 VGPR), built by prep kernel.
//  - ws layout: [0, 576KB): weight frags; [576KB, ~2.2MB): enc final h.
// ============================================================================

typedef float  f32x4  __attribute__((ext_vector_type(4)));
typedef short  bf16x8 __attribute__((ext_vector_type(8)));

struct CellB  { const float* bih; const float* bhh; const float* wih_vec; };
struct PhaseArgs {
  const float* xseq;          // [2048][512] fp32 (inputs or outputs)
  const unsigned short* frags;
  CellB cell[3];
  const float* hfin_rd;       // dec: [3][2048][64] fp32 (enc final h)
  float* hfin_wr;             // enc
  const float* lin_w;         // [60]
  const float* lin_b;         // [1]
  float* y;                   // [2048][512]
};
struct PrepArgs {
  const float* w[12];         // cell-major: (wih, whh) x 6 cells
  int din[12];
  unsigned short* out;
};

__device__ __forceinline__ unsigned int rne16(float x) {
  unsigned int u = __float_as_uint(x);
  return (u + 0x7fffu + ((u >> 16) & 1u)) >> 16;   // round-to-nearest-even bf16
}
__device__ __forceinline__ float bf2f(unsigned int b) {
  return __uint_as_float(b << 16);
}

// ---------------------------------------------------------------------------
// Prep: build B-fragments (bf16 hi/lo) for all 6 cells x {wih, whh}.
// frag layout: frag_idx = ((cell*2+mat)*12 + tile)*4 + s2*2 + sp
//              short off = frag_idx*512 + lane*8 + e
// B element at (lane,e): col c = tile*16 + (lane&15) (tiles 0-3:r,4-7:z,8-11:n)
//                        k     = s2*32 + (lane>>4)*8 + e
// ---------------------------------------------------------------------------
__global__ void prep_frags(PrepArgs P) {
  int id = blockIdx.x * 256 + threadIdx.x;       // 1152*256 = 294912 total
  int e    = id & 7;
  int lane = (id >> 3) & 63;
  int sp   = (id >> 9) & 1;
  int s2   = (id >> 10) & 1;
  int rest = id >> 11;
  int tile = rest % 12;
  int cm   = rest / 12;
  if (cm >= 12) return;
  const float* W = P.w[cm];
  int din = P.din[cm];
  int c = tile * 16 + (lane & 15);
  int j = c & 63, sec = c >> 6;                  // sec: 0=r,1=z,2=n
  int k = s2 * 32 + (lane >> 4) * 8 + e;
  float v = 0.f;
  if (j < 60 && k < din) v = W[(sec * 60 + j) * din + k];
  unsigned int hi = rne16(v);
  unsigned short o = (unsigned short)(sp ? rne16(v - bf2f(hi)) : hi);
  P.out[id] = o;
}

// ---------------------------------------------------------------------------
// A-fragment load+unpack from (hi,lo)-packed u32 LDS ring (row stride 68).
// A[r][k]: r = lane&15, k = s2*32 + (lane>>4)*8 + e
// ---------------------------------------------------------------------------
__device__ __forceinline__ void load_A(const unsigned int* rb, int c16, int q16,
                                       bf16x8 Ahi[2], bf16x8 Alo[2]) {
#pragma unroll
  for (int s2 = 0; s2 < 2; ++s2) {
    const uint4 a = *(const uint4*)(rb + c16 * 68 + s2 * 32 + q16 * 8);
    const uint4 b = *(const uint4*)(rb + c16 * 68 + s2 * 32 + q16 * 8 + 4);
    union { unsigned int u[4]; bf16x8 v; } hh, ll;
    hh.u[0] = (a.x & 0xffffu) | (a.y << 16);
    hh.u[1] = (a.z & 0xffffu) | (a.w << 16);
    hh.u[2] = (b.x & 0xffffu) | (b.y << 16);
    hh.u[3] = (b.z & 0xffffu) | (b.w << 16);
    ll.u[0] = (a.x >> 16) | (a.y & 0xffff0000u);
    ll.u[1] = (a.z >> 16) | (a.w & 0xffff0000u);
    ll.u[2] = (b.x >> 16) | (b.y & 0xffff0000u);
    ll.u[3] = (b.z >> 16) | (b.w & 0xffff0000u);
    Ahi[s2] = hh.v; Alo[s2] = ll.v;
  }
}

__device__ __forceinline__ f32x4 mm3(f32x4 acc, const bf16x8 Ahi[2],
                                     const bf16x8 Alo[2], const bf16x8 B[2][2]) {
#pragma unroll
  for (int s2 = 0; s2 < 2; ++s2) {
    acc = __builtin_amdgcn_mfma_f32_16x16x32_bf16(Ahi[s2], B[s2][0], acc, 0, 0, 0);
    acc = __builtin_amdgcn_mfma_f32_16x16x32_bf16(Alo[s2], B[s2][0], acc, 0, 0, 0);
    acc = __builtin_amdgcn_mfma_f32_16x16x32_bf16(Ahi[s2], B[s2][1], acc, 0, 0, 0);
  }
  return acc;
}

// ---------------------------------------------------------------------------
// Fused 3-stage GRU pipeline. IS_DEC=0: encoder; IS_DEC=1: decoder (+linear).
// ---------------------------------------------------------------------------
template <int IS_DEC>
__global__ __launch_bounds__(768) void gru_phase(PhaseArgs P) {
  __shared__ alignas(16) unsigned int ring[3 * 2 * 16 * 68];  // [g][par][16r][68]
  __shared__ float y_part[2][4][16];

  const int tid  = threadIdx.x;
  const int lane = tid & 63;
  const int wid  = tid >> 6;
  const int g    = wid >> 2;      // layer/cell index 0..2
  const int w    = wid & 3;       // tile-triple index 0..3
  const int c16  = lane & 15;
  const int q16  = lane >> 4;
  const int row_base = blockIdx.x * 16;
  const int c    = w * 16 + c16;  // logical h-column 0..63
  const bool cv  = (c < 60);
  const int cell = (IS_DEC ? 3 : 0) + g;
  const bool din1 = (g == 0);

  // per-lane constants
  const float* bih = P.cell[g].bih;
  const float* bhh = P.cell[g].bhh;
  float b_r  = cv ? bih[c] + bhh[c]           : 0.f;
  float b_z  = cv ? bih[60 + c] + bhh[60 + c] : 0.f;
  float b_hn = cv ? bhh[120 + c]              : 0.f;
  float b_in = cv ? bih[120 + c]              : 0.f;
  float w_r = 0.f, w_z = 0.f, w_n = 0.f;
  if (din1 && cv) {
    const float* wv = P.cell[g].wih_vec;
    w_r = wv[c]; w_z = wv[60 + c]; w_n = wv[120 + c];
  }
  float lw = 0.f, lb = 0.f;
  if (IS_DEC && g == 2) { lw = cv ? P.lin_w[c] : 0.f; lb = P.lin_b[0]; }

  // persistent weight fragments (VGPR-resident)
  bf16x8 Bh[3][2][2], Bx[3][2][2];
#pragma unroll
  for (int T = 0; T < 3; ++T)
#pragma unroll
    for (int s2 = 0; s2 < 2; ++s2)
#pragma unroll
      for (int sp = 0; sp < 2; ++sp) {
        const int tile = w + 4 * T;
        Bh[T][s2][sp] = *(const bf16x8*)(P.frags +
            (size_t)(((cell * 2 + 1) * 12 + tile) * 4 + s2 * 2 + sp) * 512 + lane * 8);
        Bx[T][s2][sp] = *(const bf16x8*)(P.frags +
            (size_t)(((cell * 2 + 0) * 12 + tile) * 4 + s2 * 2 + sp) * 512 + lane * 8);
      }

  // h0 (enc: zeros; dec: encoder final h, reversed layer order) + ring init
  float hreg[4];
#pragma unroll
  for (int q = 0; q < 4; ++q) {
    float h0 = 0.f;
    if (IS_DEC)
      h0 = P.hfin_rd[((size_t)(2 - g) * 2048 + row_base + 4 * q16 + q) * 64 + c];
    hreg[q] = h0;
    unsigned int hb = rne16(h0);
    unsigned int lo = rne16(h0 - bf2f(hb));
    ring[((g * 2 + 1) * 16 + 4 * q16 + q) * 68 + c] = hb | (lo << 16);
  }
  __syncthreads();

  const int NS = IS_DEC ? 515 : 514;
#pragma unroll 1
  for (int s = 0; s < NS; ++s) {
    // decoder: finalize y for t = s-3 (partials written last slot)
    if (IS_DEC && g == 2 && w == 0 && lane < 16) {
      int ty = s - 3;
      if (ty >= 0) {
        float yv = y_part[ty & 1][0][lane] + y_part[ty & 1][1][lane] +
                   y_part[ty & 1][2][lane] + y_part[ty & 1][3][lane] + lb;
        P.y[(size_t)(row_base + lane) * 512 + ty] = yv;
      }
    }

    const int t = s - g;
    if (t >= 0 && t < 512) {
      // ---- gh = h_{t-1} @ whh^T  (A from own ring[parity (t-1)&1])
      bf16x8 Ahi[2], Alo[2];
      load_A(ring + (g * 2 + ((t + 1) & 1)) * 16 * 68, c16, q16, Ahi, Alo);

      f32x4 aR  = {b_r, b_r, b_r, b_r};
      f32x4 aZ  = {b_z, b_z, b_z, b_z};
      f32x4 aHN = {b_hn, b_hn, b_hn, b_hn};
      f32x4 aIN = {b_in, b_in, b_in, b_in};
      aR  = mm3(aR,  Ahi, Alo, Bh[0]);
      aZ  = mm3(aZ,  Ahi, Alo, Bh[1]);
      aHN = mm3(aHN, Ahi, Alo, Bh[2]);

      // ---- gi = x @ wih^T
      if (din1) {
        const float* xp = P.xseq + (size_t)row_base * 512 + t;
#pragma unroll
        for (int q = 0; q < 4; ++q) {
          float xv = xp[(size_t)(4 * q16 + q) * 512];
          aR[q]  += xv * w_r;
          aZ[q]  += xv * w_z;
          aIN[q] += xv * w_n;
        }
      } else {
        bf16x8 Xhi[2], Xlo[2];
        load_A(ring + ((g - 1) * 2 + (t & 1)) * 16 * 68, c16, q16, Xhi, Xlo);
        aR  = mm3(aR,  Xhi, Xlo, Bx[0]);
        aZ  = mm3(aZ,  Xhi, Xlo, Bx[1]);
        aIN = mm3(aIN, Xhi, Xlo, Bx[2]);
      }

      // ---- activations + state update (full fp32)
      float hnew[4];
#pragma unroll
      for (int q = 0; q < 4; ++q) {
        float r = 1.f / (1.f + __expf(-aR[q]));
        float z = 1.f / (1.f + __expf(-aZ[q]));
        float na = aIN[q] + r * aHN[q];
        na = fminf(fmaxf(na, -15.f), 15.f);
        float e2 = __expf(2.f * na);
        float n = (e2 - 1.f) / (e2 + 1.f);
        float h = n + z * (hreg[q] - n);
        hreg[q] = h;
        hnew[q] = h;
      }

      // ---- publish h_t (hi,lo packed) to ring[parity t&1]
      {
        unsigned int* wb = ring + (g * 2 + (t & 1)) * 16 * 68;
#pragma unroll
        for (int q = 0; q < 4; ++q) {
          unsigned int hb = rne16(hnew[q]);
          unsigned int lo = rne16(hnew[q] - bf2f(hb));
          wb[(4 * q16 + q) * 68 + c] = hb | (lo << 16);
        }
      }

      // ---- encoder: store final hidden state
      if (!IS_DEC && t == 511) {
#pragma unroll
        for (int q = 0; q < 4; ++q)
          P.hfin_wr[((size_t)g * 2048 + row_base + 4 * q16 + q) * 64 + c] = hreg[q];
      }

      // ---- decoder: y partials (reduce over this wave's 16 columns)
      if (IS_DEC && g == 2) {
        float part[4];
#pragma unroll
        for (int q = 0; q < 4; ++q) part[q] = hnew[q] * lw;
#pragma unroll
        for (int m = 1; m < 16; m <<= 1) {
#pragma unroll
          for (int q = 0; q < 4; ++q) part[q] += __shfl_xor(part[q], m, 64);
        }
        if (c16 == 0) {
#pragma unroll
          for (int q = 0; q < 4; ++q) y_part[t & 1][w][4 * q16 + q] = part[q];
        }
      }
    }
    __syncthreads();
  }
}

// ---------------------------------------------------------------------------
extern "C" void kernel_launch(void* const* d_in, const int* in_sizes, int n_in,
                              void* d_out, int out_size, void* d_ws, size_t ws_size,
                              hipStream_t stream) {
  (void)in_sizes; (void)n_in; (void)out_size; (void)ws_size;
  const float* inputs  = (const float*)d_in[0];
  const float* outputs = (const float*)d_in[1];

  unsigned short* frags = (unsigned short*)d_ws;                 // 589824 B
  float* hfin = (float*)((char*)d_ws + (size_t)6 * 2 * 12 * 4 * 512 * 2); // 1.5 MB

  static const int ofs[6]  = {2, 6, 10, 14, 18, 22};  // enc0,enc1,enc2,c1,c2,c3
  static const int dins[6] = {1, 60, 60, 1, 60, 60};

  PrepArgs pa;
  for (int ci = 0; ci < 6; ++ci) {
    pa.w[ci * 2 + 0]   = (const float*)d_in[ofs[ci] + 0];  // wih
    pa.w[ci * 2 + 1]   = (const float*)d_in[ofs[ci] + 1];  // whh
    pa.din[ci * 2 + 0] = dins[ci];
    pa.din[ci * 2 + 1] = 60;
  }
  pa.out = frags;
  prep_frags<<<dim3(1152), dim3(256), 0, stream>>>(pa);

  PhaseArgs ea;
  ea.xseq = inputs; ea.frags = frags;
  for (int gg = 0; gg < 3; ++gg) {
    ea.cell[gg].bih     = (const float*)d_in[ofs[gg] + 2];
    ea.cell[gg].bhh     = (const float*)d_in[ofs[gg] + 3];
    ea.cell[gg].wih_vec = (const float*)d_in[ofs[gg] + 0];
  }
  ea.hfin_rd = hfin; ea.hfin_wr = hfin;
  ea.lin_w = (const float*)d_in[26]; ea.lin_b = (const float*)d_in[27];
  ea.y = (float*)d_out;
  gru_phase<0><<<dim3(128), dim3(768), 0, stream>>>(ea);

  PhaseArgs da = ea;
  da.xseq = outputs;
  for (int gg = 0; gg < 3; ++gg) {
    da.cell[gg].bih     = (const float*)d_in[ofs[3 + gg] + 2];
    da.cell[gg].bhh     = (const float*)d_in[ofs[3 + gg] + 3];
    da.cell[gg].wih_vec = (const float*)d_in[ofs[3 + gg] + 0];
  }
  gru_phase<1><<<dim3(128), dim3(768), 0, stream>>>(da);
}

// Round 2
// 1526.132 us; speedup vs baseline: 1.8574x; 1.8574x over previous
//
#include <hip/hip_runtime.h>
#include <hip/hip_bf16.h>

// ============================================================================
// GRU seq2seq (3-layer enc + 3-cell dec + linear), B=2048, H=60, F=1, fp32.
//
// Round 2:
//  - __launch_bounds__(768, 3): VGPR cap 170 so the 18 weight fragments stay
//    register-resident (round 1: VGPR=84 -> weights spilled to scratch, the
//    dominant per-step latency).
//  - LDS ring split into separate hi/lo bf16 planes (stride 72): A-fragment
//    reads are direct ds_read_b128, no unpack VALU (was ~128 ops/wave/step).
//  - x-path uses 2-product split (A_hi*W_hi + A_lo*W_hi); recurrent h-path
//    keeps 3-product (+ A_hi*W_lo). Saves 24 VGPR + 6 MFMA/wave/step.
//  - din=1 waves prefetch next timestep's x.
// ============================================================================

typedef float  f32x4  __attribute__((ext_vector_type(4)));
typedef short  bf16x8 __attribute__((ext_vector_type(8)));

struct CellB  { const float* bih; const float* bhh; const float* wih_vec; };
struct PhaseArgs {
  const float* xseq;          // [2048][512] fp32 (inputs or outputs)
  const unsigned short* frags;
  CellB cell[3];
  const float* hfin_rd;       // dec: [3][2048][64] fp32 (enc final h)
  float* hfin_wr;             // enc
  const float* lin_w;         // [60]
  const float* lin_b;         // [1]
  float* y;                   // [2048][512]
};
struct PrepArgs {
  const float* w[12];         // cell-major: (wih, whh) x 6 cells
  int din[12];
  unsigned short* out;
};

__device__ __forceinline__ unsigned int rne16(float x) {
  unsigned int u = __float_as_uint(x);
  return (u + 0x7fffu + ((u >> 16) & 1u)) >> 16;   // round-to-nearest-even bf16
}
__device__ __forceinline__ float bf2f(unsigned int b) {
  return __uint_as_float(b << 16);
}
union BU { __hip_bfloat16 b; unsigned short u; };
__device__ __forceinline__ unsigned short f2bf(float x) {
  BU c; c.b = __float2bfloat16(x); return c.u;
}
__device__ __forceinline__ float bfu2f(unsigned short s) {
  BU c; c.u = s; return __bfloat162float(c.b);
}

// ---------------------------------------------------------------------------
// Prep: build B-fragments (bf16 hi/lo) for all 6 cells x {wih, whh}.
// frag layout: frag_idx = ((cell*2+mat)*12 + tile)*4 + s2*2 + sp
//              short off = frag_idx*512 + lane*8 + e
// B element at (lane,e): col c = tile*16 + (lane&15) (tiles 0-3:r,4-7:z,8-11:n)
//                        k     = s2*32 + (lane>>4)*8 + e
// ---------------------------------------------------------------------------
__global__ void prep_frags(PrepArgs P) {
  int id = blockIdx.x * 256 + threadIdx.x;       // 1152*256 = 294912 total
  int e    = id & 7;
  int lane = (id >> 3) & 63;
  int sp   = (id >> 9) & 1;
  int s2   = (id >> 10) & 1;
  int rest = id >> 11;
  int tile = rest % 12;
  int cm   = rest / 12;
  if (cm >= 12) return;
  const float* W = P.w[cm];
  int din = P.din[cm];
  int c = tile * 16 + (lane & 15);
  int j = c & 63, sec = c >> 6;                  // sec: 0=r,1=z,2=n
  int k = s2 * 32 + (lane >> 4) * 8 + e;
  float v = 0.f;
  if (j < 60 && k < din) v = W[(sec * 60 + j) * din + k];
  unsigned int hi = rne16(v);
  unsigned short o = (unsigned short)(sp ? rne16(v - bf2f(hi)) : hi);
  P.out[id] = o;
}

// ---------------------------------------------------------------------------
// A-fragment loads from hi/lo bf16 planes (row stride 72 shorts = 144 B).
// A[r][k]: r = lane&15, k = s2*32 + (lane>>4)*8 + e
// ---------------------------------------------------------------------------
__device__ __forceinline__ void load_A(const unsigned short* baseH,
                                       const unsigned short* baseL,
                                       int c16, int q16,
                                       bf16x8 Ahi[2], bf16x8 Alo[2]) {
  const unsigned short* pH = baseH + c16 * 72 + q16 * 8;
  const unsigned short* pL = baseL + c16 * 72 + q16 * 8;
  Ahi[0] = *(const bf16x8*)(pH);
  Ahi[1] = *(const bf16x8*)(pH + 32);
  Alo[0] = *(const bf16x8*)(pL);
  Alo[1] = *(const bf16x8*)(pL + 32);
}

__device__ __forceinline__ f32x4 mm3(f32x4 acc, const bf16x8 Ahi[2],
                                     const bf16x8 Alo[2], const bf16x8 B[2][2]) {
#pragma unroll
  for (int s2 = 0; s2 < 2; ++s2) {
    acc = __builtin_amdgcn_mfma_f32_16x16x32_bf16(Ahi[s2], B[s2][0], acc, 0, 0, 0);
    acc = __builtin_amdgcn_mfma_f32_16x16x32_bf16(Alo[s2], B[s2][0], acc, 0, 0, 0);
    acc = __builtin_amdgcn_mfma_f32_16x16x32_bf16(Ahi[s2], B[s2][1], acc, 0, 0, 0);
  }
  return acc;
}

__device__ __forceinline__ f32x4 mm2(f32x4 acc, const bf16x8 Ahi[2],
                                     const bf16x8 Alo[2], const bf16x8 B[2]) {
#pragma unroll
  for (int s2 = 0; s2 < 2; ++s2) {
    acc = __builtin_amdgcn_mfma_f32_16x16x32_bf16(Ahi[s2], B[s2], acc, 0, 0, 0);
    acc = __builtin_amdgcn_mfma_f32_16x16x32_bf16(Alo[s2], B[s2], acc, 0, 0, 0);
  }
  return acc;
}

// ---------------------------------------------------------------------------
// Fused 3-stage GRU pipeline. IS_DEC=0: encoder; IS_DEC=1: decoder (+linear).
// ---------------------------------------------------------------------------
template <int IS_DEC>
__global__ __launch_bounds__(768, 3) void gru_phase(PhaseArgs P) {
  __shared__ alignas(16) unsigned short ringH[3 * 2 * 16 * 72];
  __shared__ alignas(16) unsigned short ringL[3 * 2 * 16 * 72];
  __shared__ float y_part[2][4][16];

  const int tid  = threadIdx.x;
  const int lane = tid & 63;
  const int wid  = tid >> 6;
  const int g    = wid >> 2;      // layer/cell index 0..2
  const int w    = wid & 3;       // tile-triple index 0..3
  const int c16  = lane & 15;
  const int q16  = lane >> 4;
  const int row_base = blockIdx.x * 16;
  const int c    = w * 16 + c16;  // logical h-column 0..63
  const bool cv  = (c < 60);
  const int cell = (IS_DEC ? 3 : 0) + g;
  const bool din1 = (g == 0);

  // per-lane constants
  const float* bih = P.cell[g].bih;
  const float* bhh = P.cell[g].bhh;
  float b_r  = cv ? bih[c] + bhh[c]           : 0.f;
  float b_z  = cv ? bih[60 + c] + bhh[60 + c] : 0.f;
  float b_hn = cv ? bhh[120 + c]              : 0.f;
  float b_in = cv ? bih[120 + c]              : 0.f;
  float w_r = 0.f, w_z = 0.f, w_n = 0.f;
  if (din1 && cv) {
    const float* wv = P.cell[g].wih_vec;
    w_r = wv[c]; w_z = wv[60 + c]; w_n = wv[120 + c];
  }
  float lw = 0.f, lb = 0.f;
  if (IS_DEC && g == 2) { lw = cv ? P.lin_w[c] : 0.f; lb = P.lin_b[0]; }

  // persistent weight fragments (VGPR-resident)
  // Bh: 3 gates x 2 k-slices x {W_hi, W_lo}  (48 VGPR)
  // Bx: 3 gates x 2 k-slices, W_hi only      (24 VGPR)
  bf16x8 Bh[3][2][2], Bx[3][2];
#pragma unroll
  for (int T = 0; T < 3; ++T)
#pragma unroll
    for (int s2 = 0; s2 < 2; ++s2) {
      const int tile = w + 4 * T;
#pragma unroll
      for (int sp = 0; sp < 2; ++sp)
        Bh[T][s2][sp] = *(const bf16x8*)(P.frags +
            (size_t)(((cell * 2 + 1) * 12 + tile) * 4 + s2 * 2 + sp) * 512 + lane * 8);
      Bx[T][s2] = *(const bf16x8*)(P.frags +
          (size_t)(((cell * 2 + 0) * 12 + tile) * 4 + s2 * 2 + 0) * 512 + lane * 8);
    }

  // h0 (enc: zeros; dec: encoder final h, reversed layer order) + ring init
  float hreg[4];
#pragma unroll
  for (int q = 0; q < 4; ++q) {
    float h0 = 0.f;
    if (IS_DEC)
      h0 = P.hfin_rd[((size_t)(2 - g) * 2048 + row_base + 4 * q16 + q) * 64 + c];
    hreg[q] = h0;
    unsigned short hb = f2bf(h0);
    unsigned short lo = f2bf(h0 - bfu2f(hb));
    int ro = ((g * 2 + 1) * 16 + 4 * q16 + q) * 72 + c;
    ringH[ro] = hb; ringL[ro] = lo;
  }

  // x prefetch (t=0) for din=1 waves
  float xcur[4];
  if (din1) {
    const float* xp = P.xseq + (size_t)row_base * 512;
#pragma unroll
    for (int q = 0; q < 4; ++q) xcur[q] = xp[(size_t)(4 * q16 + q) * 512];
  }
  __syncthreads();

  const int NS = IS_DEC ? 515 : 514;
#pragma unroll 1
  for (int s = 0; s < NS; ++s) {
    // decoder: finalize y for t = s-3 (partials written last slot)
    if (IS_DEC && g == 2 && w == 0 && lane < 16) {
      int ty = s - 3;
      if (ty >= 0) {
        float yv = y_part[ty & 1][0][lane] + y_part[ty & 1][1][lane] +
                   y_part[ty & 1][2][lane] + y_part[ty & 1][3][lane] + lb;
        P.y[(size_t)(row_base + lane) * 512 + ty] = yv;
      }
    }

    const int t = s - g;
    if (t >= 0 && t < 512) {
      // ---- gh = h_{t-1} @ whh^T  (A from own ring[parity (t-1)&1])
      const int rdo = (g * 2 + ((t + 1) & 1)) * 16 * 72;
      bf16x8 Ahi[2], Alo[2];
      load_A(ringH + rdo, ringL + rdo, c16, q16, Ahi, Alo);

      f32x4 aR  = {b_r, b_r, b_r, b_r};
      f32x4 aZ  = {b_z, b_z, b_z, b_z};
      f32x4 aHN = {b_hn, b_hn, b_hn, b_hn};
      f32x4 aIN = {b_in, b_in, b_in, b_in};
      aR  = mm3(aR,  Ahi, Alo, Bh[0]);
      aZ  = mm3(aZ,  Ahi, Alo, Bh[1]);
      aHN = mm3(aHN, Ahi, Alo, Bh[2]);

      // ---- gi = x @ wih^T
      if (din1) {
#pragma unroll
        for (int q = 0; q < 4; ++q) {
          aR[q]  += xcur[q] * w_r;
          aZ[q]  += xcur[q] * w_z;
          aIN[q] += xcur[q] * w_n;
        }
        if (t + 1 < 512) {                      // prefetch next step's x
          const float* xp = P.xseq + (size_t)row_base * 512 + (t + 1);
#pragma unroll
          for (int q = 0; q < 4; ++q) xcur[q] = xp[(size_t)(4 * q16 + q) * 512];
        }
      } else {
        const int rxo = ((g - 1) * 2 + (t & 1)) * 16 * 72;
        bf16x8 Xhi[2], Xlo[2];
        load_A(ringH + rxo, ringL + rxo, c16, q16, Xhi, Xlo);
        aR  = mm2(aR,  Xhi, Xlo, Bx[0]);
        aZ  = mm2(aZ,  Xhi, Xlo, Bx[1]);
        aIN = mm2(aIN, Xhi, Xlo, Bx[2]);
      }

      // ---- activations + state update (full fp32)
#pragma unroll
      for (int q = 0; q < 4; ++q) {
        float r = __builtin_amdgcn_rcpf(1.f + __expf(-aR[q]));
        float z = __builtin_amdgcn_rcpf(1.f + __expf(-aZ[q]));
        float na = aIN[q] + r * aHN[q];
        na = fminf(fmaxf(na, -15.f), 15.f);
        float e2 = __expf(2.f * na);
        float n = (e2 - 1.f) * __builtin_amdgcn_rcpf(e2 + 1.f);
        hreg[q] = n + z * (hreg[q] - n);
      }

      // ---- publish h_t (hi/lo planes) to ring[parity t&1]
      {
        unsigned short* wH = ringH + (g * 2 + (t & 1)) * 16 * 72;
        unsigned short* wL = ringL + (g * 2 + (t & 1)) * 16 * 72;
#pragma unroll
        for (int q = 0; q < 4; ++q) {
          float h = hreg[q];
          unsigned short hb = f2bf(h);
          unsigned short lo = f2bf(h - bfu2f(hb));
          int ro = (4 * q16 + q) * 72 + c;
          wH[ro] = hb; wL[ro] = lo;
        }
      }

      // ---- encoder: store final hidden state
      if (!IS_DEC && t == 511) {
#pragma unroll
        for (int q = 0; q < 4; ++q)
          P.hfin_wr[((size_t)g * 2048 + row_base + 4 * q16 + q) * 64 + c] = hreg[q];
      }

      // ---- decoder: y partials (reduce over this wave's 16 columns)
      if (IS_DEC && g == 2) {
        float part[4];
#pragma unroll
        for (int q = 0; q < 4; ++q) part[q] = hreg[q] * lw;
#pragma unroll
        for (int m = 1; m < 16; m <<= 1) {
#pragma unroll
          for (int q = 0; q < 4; ++q) part[q] += __shfl_xor(part[q], m, 64);
        }
        if (c16 == 0) {
#pragma unroll
          for (int q = 0; q < 4; ++q) y_part[t & 1][w][4 * q16 + q] = part[q];
        }
      }
    }
    __syncthreads();
  }
}

// ---------------------------------------------------------------------------
extern "C" void kernel_launch(void* const* d_in, const int* in_sizes, int n_in,
                              void* d_out, int out_size, void* d_ws, size_t ws_size,
                              hipStream_t stream) {
  (void)in_sizes; (void)n_in; (void)out_size; (void)ws_size;
  const float* inputs  = (const float*)d_in[0];
  const float* outputs = (const float*)d_in[1];

  unsigned short* frags = (unsigned short*)d_ws;                 // 589824 B
  float* hfin = (float*)((char*)d_ws + (size_t)6 * 2 * 12 * 4 * 512 * 2); // 1.5 MB

  static const int ofs[6]  = {2, 6, 10, 14, 18, 22};  // enc0,enc1,enc2,c1,c2,c3
  static const int dins[6] = {1, 60, 60, 1, 60, 60};

  PrepArgs pa;
  for (int ci = 0; ci < 6; ++ci) {
    pa.w[ci * 2 + 0]   = (const float*)d_in[ofs[ci] + 0];  // wih
    pa.w[ci * 2 + 1]   = (const float*)d_in[ofs[ci] + 1];  // whh
    pa.din[ci * 2 + 0] = dins[ci];
    pa.din[ci * 2 + 1] = 60;
  }
  pa.out = frags;
  prep_frags<<<dim3(1152), dim3(256), 0, stream>>>(pa);

  PhaseArgs ea;
  ea.xseq = inputs; ea.frags = frags;
  for (int gg = 0; gg < 3; ++gg) {
    ea.cell[gg].bih     = (const float*)d_in[ofs[gg] + 2];
    ea.cell[gg].bhh     = (const float*)d_in[ofs[gg] + 3];
    ea.cell[gg].wih_vec = (const float*)d_in[ofs[gg] + 0];
  }
  ea.hfin_rd = hfin; ea.hfin_wr = hfin;
  ea.lin_w = (const float*)d_in[26]; ea.lin_b = (const float*)d_in[27];
  ea.y = (float*)d_out;
  gru_phase<0><<<dim3(128), dim3(768), 0, stream>>>(ea);

  PhaseArgs da = ea;
  da.xseq = outputs;
  for (int gg = 0; gg < 3; ++gg) {
    da.cell[gg].bih     = (const float*)d_in[ofs[3 + gg] + 2];
    da.cell[gg].bhh     = (const float*)d_in[ofs[3 + gg] + 3];
    da.cell[gg].wih_vec = (const float*)d_in[ofs[3 + gg] + 0];
  }
  gru_phase<1><<<dim3(128), dim3(768), 0, stream>>>(da);
}